// Round 1
// baseline (3574.487 us; speedup 1.0000x reference)
//
#include <hip/hip_runtime.h>
#include <cstddef>

#define NN 50000
#define FF 16
#define TT 12
#define HH 128
#define EE 800000
#define OO 16

// ---------------- degree / normalization ----------------
__global__ void k_deg(const int* __restrict__ ei, const float* __restrict__ ew,
                      float* __restrict__ deg) {
  int e = blockIdx.x * 256 + threadIdx.x;
  if (e < EE) atomicAdd(&deg[ei[EE + e]], ew[e]);
}

__global__ void k_dinv(float* __restrict__ deg) {
  int n = blockIdx.x * 256 + threadIdx.x;
  if (n < NN) deg[n] = rsqrtf(deg[n] + 1.0f);  // self-loop weight 1 included
}

// Y[t][n][f] = dinv[n]^2 * x[n][f][t]   (self-loop term; full overwrite of Y)
__global__ void k_inity(const float* __restrict__ x, const float* __restrict__ dinv,
                        float* __restrict__ Y) {
  int tid = blockIdx.x * 256 + threadIdx.x;  // t*(N*4) + n*4 + f4
  if (tid >= TT * NN * 4) return;
  int t = tid / (NN * 4);
  int rem = tid - t * (NN * 4);
  int n = rem >> 2, f4 = rem & 3;
  float dv = dinv[n];
  dv *= dv;
  const float* xr = x + (size_t)n * (FF * TT);
  float4 v;
  v.x = dv * xr[(f4 * 4 + 0) * TT + t];
  v.y = dv * xr[(f4 * 4 + 1) * TT + t];
  v.z = dv * xr[(f4 * 4 + 2) * TT + t];
  v.w = dv * xr[(f4 * 4 + 3) * TT + t];
  *(float4*)&Y[((size_t)t * NN + n) * 16 + f4 * 4] = v;
}

// one wave per edge: lane covers 3 of the 192 columns (coalesced x reads)
__global__ void k_edges(const int* __restrict__ ei, const float* __restrict__ ew,
                        const float* __restrict__ dinv, const float* __restrict__ x,
                        float* __restrict__ Y) {
  long long gt = (long long)blockIdx.x * 256 + threadIdx.x;
  int wid = (int)(gt >> 6);
  if (wid >= EE) return;
  int lane = threadIdx.x & 63;
  int s = ei[wid], d = ei[EE + wid];
  float nrm = dinv[s] * ew[wid] * dinv[d];
  const float* xr = x + (size_t)s * (FF * TT);
#pragma unroll
  for (int i = 0; i < 3; i++) {
    int c = lane + 64 * i;        // c = f*12 + t
    int t = c % TT, f = c / TT;
    atomicAdd(&Y[((size_t)t * NN + d) * 16 + f], nrm * xr[c]);
  }
}

// ---------------- fused weight prep: A = conv_w @ lin_top, bfv = conv_b @ lin_top + lin_b
__global__ void k_prep(const float* __restrict__ czw, const float* __restrict__ czb,
                       const float* __restrict__ lzw, const float* __restrict__ lzb,
                       const float* __restrict__ crw, const float* __restrict__ crb,
                       const float* __restrict__ lrw, const float* __restrict__ lrb,
                       const float* __restrict__ chw, const float* __restrict__ chb,
                       const float* __restrict__ lhw, const float* __restrict__ lhb,
                       float* __restrict__ A, float* __restrict__ bfv) {
  const float *cw, *cb, *lw, *lb;
  if (blockIdx.x == 0)      { cw = czw; cb = czb; lw = lzw; lb = lzb; }
  else if (blockIdx.x == 1) { cw = crw; cb = crb; lw = lrw; lb = lrb; }
  else                      { cw = chw; cb = chb; lw = lhw; lb = lhb; }
  float* Ao = A + blockIdx.x * 2048;
  float* bo = bfv + blockIdx.x * 128;
  for (int idx = threadIdx.x; idx < 2048; idx += 256) {
    int f = idx >> 7, j = idx & 127;
    float acc = 0.f;
    for (int k = 0; k < 128; k++) acc = fmaf(cw[f * 128 + k], lw[k * 128 + j], acc);
    Ao[idx] = acc;
  }
  for (int j = threadIdx.x; j < 128; j += 256) {
    float acc = lb[j];
    for (int k = 0; k < 128; k++) acc = fmaf(cb[k], lw[k * 128 + j], acc);
    bo[j] = acc;
  }
}

// ---------------- main fused GRU + attention + output ----------------
__device__ __forceinline__ void stage2048(float* wl, const float* __restrict__ g, int tid) {
  float4* d4 = (float4*)wl;
  const float4* s4 = (const float4*)g;
  d4[tid] = s4[tid];
  d4[tid + 256] = s4[tid + 256];
}

__device__ __forceinline__ void mm_chunk16(float acc[4][8], const float* src, int stride,
                                           int kbase, float (*w)[128], int rg, int c0) {
#pragma unroll
  for (int k = 0; k < 16; k++) {
    float4 wa = *(const float4*)&w[k][c0];
    float4 wb = *(const float4*)&w[k][c0 + 4];
#pragma unroll
    for (int i = 0; i < 4; i++) {
      float hv = src[(rg * 4 + i) * stride + kbase + k];
      acc[i][0] = fmaf(hv, wa.x, acc[i][0]);
      acc[i][1] = fmaf(hv, wa.y, acc[i][1]);
      acc[i][2] = fmaf(hv, wa.z, acc[i][2]);
      acc[i][3] = fmaf(hv, wa.w, acc[i][3]);
      acc[i][4] = fmaf(hv, wb.x, acc[i][4]);
      acc[i][5] = fmaf(hv, wb.y, acc[i][5]);
      acc[i][6] = fmaf(hv, wb.z, acc[i][6]);
      acc[i][7] = fmaf(hv, wb.w, acc[i][7]);
    }
  }
}

__device__ __forceinline__ void mm16(float acc[4][8], const float* ysrc,
                                     const float* __restrict__ Af, float (*w)[128],
                                     int rg, int c0, int tid) {
  stage2048(&w[0][0], Af, tid);
  __syncthreads();
  mm_chunk16(acc, ysrc, 16, 0, w, rg, c0);
  __syncthreads();
}

__device__ __forceinline__ void mm128(float acc[4][8], const float* src, int stride,
                                      const float* __restrict__ B, float (*w)[128],
                                      int rg, int c0, int tid) {
  for (int kk = 0; kk < 8; kk++) {
    stage2048(&w[0][0], B + kk * 2048, tid);
    __syncthreads();
    mm_chunk16(acc, src, stride, kk * 16, w, rg, c0);
    __syncthreads();
  }
}

__global__ __launch_bounds__(256, 2) void k_main(
    const float* __restrict__ Y, const float* __restrict__ A, const float* __restrict__ bfv,
    const float* __restrict__ lzw, const float* __restrict__ lrw, const float* __restrict__ lhw,
    const float* __restrict__ a1w, const float* __restrict__ a1b,
    const float* __restrict__ a2w, const float* __restrict__ a2b,
    const float* __restrict__ ow, const float* __restrict__ ob,
    float* __restrict__ out) {
  __shared__ float h_lds[64][132];
  __shared__ float u_lds[64][132];
  __shared__ float y_lds[64][16];
  __shared__ float w_lds[16][128];
  const int tid = threadIdx.x;
  const int cg = tid & 15, rg = tid >> 4;
  const int c0 = cg * 8;
  const int base = blockIdx.x * 64;

#pragma unroll
  for (int i = 0; i < 4; i++) {
    *(float4*)&h_lds[rg * 4 + i][c0] = make_float4(0.f, 0.f, 0.f, 0.f);
    *(float4*)&h_lds[rg * 4 + i][c0 + 4] = make_float4(0.f, 0.f, 0.f, 0.f);
  }

  float bz[8], brr[8], bh[8], ab1[8], a2r[8];
#pragma unroll
  for (int j = 0; j < 8; j++) {
    bz[j] = bfv[c0 + j];
    brr[j] = bfv[128 + c0 + j];
    bh[j] = bfv[256 + c0 + j];
    ab1[j] = a1b[c0 + j];
    a2r[j] = a2w[c0 + j];
  }
  float b2 = a2b[0];

  float ctx[4][8], mrun[4], srun[4];
#pragma unroll
  for (int i = 0; i < 4; i++) {
    mrun[i] = -1e30f;
    srun[i] = 0.f;
#pragma unroll
    for (int j = 0; j < 8; j++) ctx[i][j] = 0.f;
  }
  __syncthreads();

  for (int t = 0; t < TT; t++) {
    {  // stage Y_t (coalesced float4)
      int row = tid >> 2, f4 = tid & 3;
      int gr = base + row;
      float4 v = make_float4(0.f, 0.f, 0.f, 0.f);
      if (gr < NN) v = *(const float4*)&Y[((size_t)t * NN + gr) * 16 + f4 * 4];
      *(float4*)&y_lds[row][f4 * 4] = v;
    }
    __syncthreads();

    float accz[4][8], accr[4][8];
#pragma unroll
    for (int i = 0; i < 4; i++)
#pragma unroll
      for (int j = 0; j < 8; j++) { accz[i][j] = bz[j]; accr[i][j] = brr[j]; }

    mm16(accz, &y_lds[0][0], A, w_lds, rg, c0, tid);
    mm128(accz, &h_lds[0][0], 132, lzw + HH * HH, w_lds, rg, c0, tid);
    mm16(accr, &y_lds[0][0], A + 2048, w_lds, rg, c0, tid);
    mm128(accr, &h_lds[0][0], 132, lrw + HH * HH, w_lds, rg, c0, tid);

    float z[4][8], ho[4][8];
#pragma unroll
    for (int i = 0; i < 4; i++) {
      float4 h0 = *(const float4*)&h_lds[rg * 4 + i][c0];
      float4 h1 = *(const float4*)&h_lds[rg * 4 + i][c0 + 4];
      ho[i][0] = h0.x; ho[i][1] = h0.y; ho[i][2] = h0.z; ho[i][3] = h0.w;
      ho[i][4] = h1.x; ho[i][5] = h1.y; ho[i][6] = h1.z; ho[i][7] = h1.w;
      float u[8];
#pragma unroll
      for (int j = 0; j < 8; j++) {
        z[i][j] = 1.f / (1.f + __expf(-accz[i][j]));
        float rr = 1.f / (1.f + __expf(-accr[i][j]));
        u[j] = ho[i][j] * rr;
      }
      *(float4*)&u_lds[rg * 4 + i][c0] = make_float4(u[0], u[1], u[2], u[3]);
      *(float4*)&u_lds[rg * 4 + i][c0 + 4] = make_float4(u[4], u[5], u[6], u[7]);
    }
    __syncthreads();

    float acch[4][8];
#pragma unroll
    for (int i = 0; i < 4; i++)
#pragma unroll
      for (int j = 0; j < 8; j++) acch[i][j] = bh[j];
    mm16(acch, &y_lds[0][0], A + 4096, w_lds, rg, c0, tid);
    mm128(acch, &u_lds[0][0], 132, lhw + HH * HH, w_lds, rg, c0, tid);

    float hn[4][8];
#pragma unroll
    for (int i = 0; i < 4; i++)
#pragma unroll
      for (int j = 0; j < 8; j++) {
        float th = 2.f / (1.f + __expf(-2.f * acch[i][j])) - 1.f;
        hn[i][j] = z[i][j] * ho[i][j] + (1.f - z[i][j]) * th;
      }
    // all h_lds readers finished before the u_lds barrier; mm barriers since
#pragma unroll
    for (int i = 0; i < 4; i++) {
      *(float4*)&h_lds[rg * 4 + i][c0] = make_float4(hn[i][0], hn[i][1], hn[i][2], hn[i][3]);
      *(float4*)&h_lds[rg * 4 + i][c0 + 4] = make_float4(hn[i][4], hn[i][5], hn[i][6], hn[i][7]);
    }
    __syncthreads();

    float accg[4][8];
#pragma unroll
    for (int i = 0; i < 4; i++)
#pragma unroll
      for (int j = 0; j < 8; j++) accg[i][j] = ab1[j];
    mm128(accg, &h_lds[0][0], 132, a1w, w_lds, rg, c0, tid);

#pragma unroll
    for (int i = 0; i < 4; i++) {
      float p = 0.f;
#pragma unroll
      for (int j = 0; j < 8; j++) p = fmaf(fmaxf(accg[i][j], 0.f), a2r[j], p);
      p += __shfl_xor(p, 1, 64);
      p += __shfl_xor(p, 2, 64);
      p += __shfl_xor(p, 4, 64);
      p += __shfl_xor(p, 8, 64);
      float e = p + b2;
      float mn = fmaxf(mrun[i], e);
      float al = __expf(mrun[i] - mn);
      float be = __expf(e - mn);
      srun[i] = srun[i] * al + be;
      mrun[i] = mn;
#pragma unroll
      for (int j = 0; j < 8; j++) ctx[i][j] = ctx[i][j] * al + be * hn[i][j];
    }
  }

  // epilogue: out = (ctx/s) @ out_w + out_b
  stage2048(&w_lds[0][0], ow, tid);
  __syncthreads();
  float po[4][16];
#pragma unroll
  for (int i = 0; i < 4; i++) {
    float inv = 1.f / srun[i];
#pragma unroll
    for (int o = 0; o < 16; o++) po[i][o] = 0.f;
#pragma unroll
    for (int j = 0; j < 8; j++) {
      float c = ctx[i][j] * inv;
      const float* wr = &w_lds[0][0] + (c0 + j) * 16;
#pragma unroll
      for (int o = 0; o < 16; o++) po[i][o] = fmaf(c, wr[o], po[i][o]);
    }
  }
#pragma unroll
  for (int mask = 1; mask < 16; mask <<= 1)
#pragma unroll
    for (int i = 0; i < 4; i++)
#pragma unroll
      for (int o = 0; o < 16; o++) po[i][o] += __shfl_xor(po[i][o], mask, 64);
  float obv = ob[cg];
#pragma unroll
  for (int i = 0; i < 4; i++) {
    int gr = base + rg * 4 + i;
    if (gr < NN) out[gr * 16 + cg] = po[i][cg] + obv;
  }
}

extern "C" void kernel_launch(void* const* d_in, const int* in_sizes, int n_in,
                              void* d_out, int out_size, void* d_ws, size_t ws_size,
                              hipStream_t stream) {
  const float* x   = (const float*)d_in[0];
  const int*   ei  = (const int*)d_in[1];
  const float* ew  = (const float*)d_in[2];
  const float* czw = (const float*)d_in[3],  *czb = (const float*)d_in[4];
  const float* crw = (const float*)d_in[5],  *crb = (const float*)d_in[6];
  const float* chw = (const float*)d_in[7],  *chb = (const float*)d_in[8];
  const float* lzw = (const float*)d_in[9],  *lzb = (const float*)d_in[10];
  const float* lrw = (const float*)d_in[11], *lrb = (const float*)d_in[12];
  const float* lhw = (const float*)d_in[13], *lhb = (const float*)d_in[14];
  const float* a1w = (const float*)d_in[15], *a1b = (const float*)d_in[16];
  const float* a2w = (const float*)d_in[17], *a2b = (const float*)d_in[18];
  const float* ow  = (const float*)d_in[19], *ob  = (const float*)d_in[20];

  float* ws  = (float*)d_ws;
  float* deg = ws;            // N (becomes dinv)
  float* A   = ws + 50048;    // 3*16*128 fused conv@lin_top
  float* bfv = ws + 56192;    // 3*128 fused biases
  float* Y   = ws + 56576;    // [T][N][16] propagated features
  float* out = (float*)d_out;

  hipMemsetAsync(deg, 0, NN * sizeof(float), stream);
  k_deg<<<(EE + 255) / 256, 256, 0, stream>>>(ei, ew, deg);
  k_dinv<<<(NN + 255) / 256, 256, 0, stream>>>(deg);
  k_inity<<<(TT * NN * 4 + 255) / 256, 256, 0, stream>>>(x, deg, Y);
  k_edges<<<(EE * 64) / 256, 256, 0, stream>>>(ei, ew, deg, x, Y);
  k_prep<<<3, 256, 0, stream>>>(czw, czb, lzw, lzb, crw, crb, lrw, lrb,
                                chw, chb, lhw, lhb, A, bfv);
  k_main<<<(NN + 63) / 64, 256, 0, stream>>>(Y, A, bfv, lzw, lrw, lhw,
                                             a1w, a1b, a2w, a2b, ow, ob, out);
}